// Round 12
// baseline (99.888 us; speedup 1.0000x reference)
//
#include <hip/hip_runtime.h>
#include <hip/hip_bf16.h>
#include <stdint.h>

// Problem constants (B=2, T=2048, D=1024, H=16, DH=64)
#define Bn  2
#define Tn  2048
#define Dn  1024
#define Hn  16
#define DHn 64
#define QSCALE 0.1803368801111204f   // 0.125 * log2(e): fold softmax scale + exp2 into Q

typedef unsigned short u16;
typedef __attribute__((ext_vector_type(8))) short s16x8;            // 8 bf16 MFMA frag
typedef __attribute__((ext_vector_type(8))) unsigned short u16x8;
typedef __attribute__((ext_vector_type(4))) unsigned short u16x4;
typedef __attribute__((ext_vector_type(4))) float f32x4;

#define MFMA(a, b, c) __builtin_amdgcn_mfma_f32_16x16x32_bf16((a), (b), (c), 0, 0, 0)

__device__ __forceinline__ u16 f2bf(float f) {
  union { __hip_bfloat16 b; u16 u; } c;
  c.b = __float2bfloat16(f);
  return c.u;
}
__device__ __forceinline__ float bf2f(u16 u) {
  union { u16 u; __hip_bfloat16 b; } c;
  c.u = u;
  return __bfloat162float(c.b);
}

// async global->LDS, 16B per lane; LDS dest is wave-uniform base (+lane*16)
__device__ __forceinline__ void lds16(void* lds, const void* g) {
  __builtin_amdgcn_global_load_lds((__attribute__((address_space(1))) void*)(g),
                                   (__attribute__((address_space(3))) void*)(lds), 16, 0, 0);
}

// ---------------------------------------------------------------------------
// fp32 -> bf16 bulk convert: x, W_qkv, W_o in ONE launch.
// x+W_qkv dests are adjacent (d01); W_o goes to its own region (d2).
// ---------------------------------------------------------------------------
__global__ __launch_bounds__(256) void k_cvt3(
    const float* __restrict__ s0, int n0,
    const float* __restrict__ s1, int n1,
    const float* __restrict__ s2, int n2,
    u16* __restrict__ d01, u16* __restrict__ d2) {
  int i = blockIdx.x * blockDim.x + threadIdx.x;
  const int stride = gridDim.x * blockDim.x;
  const int nt = n0 + n1 + n2;
  for (; i < nt; i += stride) {
    float4 v;
    u16x4 o;
    if (i < n0 + n1) {
      v = (i < n0) ? ((const float4*)s0)[i] : ((const float4*)s1)[i - n0];
      o[0] = f2bf(v.x); o[1] = f2bf(v.y); o[2] = f2bf(v.z); o[3] = f2bf(v.w);
      ((u16x4*)d01)[i] = o;
    } else {
      v = ((const float4*)s2)[i - n0 - n1];
      o[0] = f2bf(v.x); o[1] = f2bf(v.y); o[2] = f2bf(v.z); o[3] = f2bf(v.w);
      ((u16x4*)d2)[i - n0 - n1] = o;
    }
  }
}

// ---------------------------------------------------------------------------
// Kernel 1: qkv = x @ W_qkv^T (M=4096, N=3072, K=1024).
// BK=32, depth-2 counted-vmcnt pipeline, 34.8KB LDS -> 4 blocks/CU.
// XOR-granule swizzle: linear LDS dest (gload_lds), pre-swizzled global
// source, swizzled frag reads. Blocks pure Q(0-7)/K(8-15)/V(16-23).
// Epilogue: acc -> LDS (stride 136); Q/K RoPE + coalesced stores; V
// column-transpose -> V^T [b,h,dh,t].
// ---------------------------------------------------------------------------
__global__ __launch_bounds__(256) void k_qkv(
    const u16* __restrict__ xb, const u16* __restrict__ wb,
    const int* __restrict__ tokpos,
    const float* __restrict__ cosc, const float* __restrict__ sinc,
    u16* __restrict__ qb, u16* __restrict__ kb, u16* __restrict__ vtb)
{
  __shared__ u16 smem[17408];           // loop: As0|As1|Bs0|Bs1 (8KB each); epi 34.8KB
  const int tid  = threadIdx.x;
  const int bcol = blockIdx.x;          // 24 tiles of N=3072
  const int brow = blockIdx.y;          // 32 tiles of M=4096
  const int lane = tid & 63, w = tid >> 6;
  const int wr = w >> 1, wc = w & 1;
  const int l15 = lane & 15, l4 = lane >> 4;
  const int lrow = lane >> 2;                        // 0..15 (4 lanes/32-elem row)
  const int gsw  = (((lane & 3) ^ ((lrow >> 1) & 3)) * 8);  // src granule (u16 units)
  const int rsw  = (l15 >> 1) & 3;                   // frag-read granule XOR

  const u16* xrow = xb + (size_t)(brow * 128) * 1024;
  const u16* wrow = wb + (size_t)(bcol * 128) * 1024;

  f32x4 acc[4][4] = {};

  // prologue: stage k-step 0 into buf0 (4 lds16 per wave)
  {
    const int r0 = w * 32;
    lds16(&smem[r0 * 32],              xrow + (size_t)(r0 + lrow) * 1024 + gsw);
    lds16(&smem[(r0 + 16) * 32],       xrow + (size_t)(r0 + 16 + lrow) * 1024 + gsw);
    lds16(&smem[8192 + r0 * 32],       wrow + (size_t)(r0 + lrow) * 1024 + gsw);
    lds16(&smem[8192 + (r0 + 16) * 32],wrow + (size_t)(r0 + 16 + lrow) * 1024 + gsw);
  }

  for (int kt = 0; kt < 32; ++kt) {
    const int cur = kt & 1;
    const u16* Asb = smem + cur * 4096;
    const u16* Bsb = smem + 8192 + cur * 4096;
    if (kt < 31) {                       // stage(t+1): stays in flight through compute
      u16* Asn = smem + (cur ^ 1) * 4096;
      u16* Bsn = smem + 8192 + (cur ^ 1) * 4096;
      const int k1 = (kt + 1) * 32;
      const int r0 = w * 32;
      lds16(&Asn[r0 * 32],        xrow + (size_t)(r0 + lrow) * 1024 + k1 + gsw);
      lds16(&Asn[(r0 + 16) * 32], xrow + (size_t)(r0 + 16 + lrow) * 1024 + k1 + gsw);
      lds16(&Bsn[r0 * 32],        wrow + (size_t)(r0 + lrow) * 1024 + k1 + gsw);
      lds16(&Bsn[(r0 + 16) * 32], wrow + (size_t)(r0 + 16 + lrow) * 1024 + k1 + gsw);
      asm volatile("s_waitcnt vmcnt(4)" ::: "memory");   // stage(t) complete
    } else {
      asm volatile("s_waitcnt vmcnt(0)" ::: "memory");
    }
    __builtin_amdgcn_s_barrier();        // buf(t) visible to all waves
    __builtin_amdgcn_sched_barrier(0);
    __builtin_amdgcn_s_setprio(1);
    {
      const int gr = (l4 ^ rsw) * 8;
      s16x8 af[4], bf[4];
#pragma unroll
      for (int m = 0; m < 4; ++m)
        af[m] = *(const s16x8*)&Asb[(wr * 64 + m * 16 + l15) * 32 + gr];
#pragma unroll
      for (int n = 0; n < 4; ++n)
        bf[n] = *(const s16x8*)&Bsb[(wc * 64 + n * 16 + l15) * 32 + gr];
#pragma unroll
      for (int m = 0; m < 4; ++m)
#pragma unroll
        for (int n = 0; n < 4; ++n)
          acc[m][n] = MFMA(af[m], bf[n], acc[m][n]);
    }
    __builtin_amdgcn_s_setprio(0);
    __builtin_amdgcn_sched_barrier(0);
    __builtin_amdgcn_s_barrier();        // all reads of buf(t) done before overwrite
  }

  // ---- epilogue phase 1: raw acc -> Ct (bf16, stride 136) ----
#pragma unroll
  for (int m = 0; m < 4; ++m)
#pragma unroll
    for (int n = 0; n < 4; ++n)
#pragma unroll
      for (int r = 0; r < 4; ++r)
        smem[(wr * 64 + m * 16 + l4 * 4 + r) * 136 + wc * 64 + n * 16 + l15] =
            f2bf(acc[m][n][r]);
  __syncthreads();

  if (bcol < 16) {
    // ---- Q/K: re-read rows, RoPE in-register, coalesced 16B stores ----
    u16* dst; float sc;
    if (bcol < 8) { dst = qb; sc = QSCALE; } else { dst = kb; sc = 1.0f; }
#pragma unroll
    for (int ph = 0; ph < 8; ++ph) {
      const int task = ph * 256 + tid;
      const int lr   = task >> 4;          // 0..127
      const int cg   = task & 15;          // col group (8 elems)
      const int rowg = brow * 128 + lr;
      const int b = rowg >> 11, t = rowg & 2047;
      const int rem = (bcol * 128 + cg * 8) & 1023;
      const int h = rem >> 6, dh0 = rem & 63;
      u16x8 v = *(const u16x8*)&smem[lr * 136 + cg * 8];
      const int pos = tokpos[t];
      const float4 cv = *(const float4*)&cosc[pos * 32 + (dh0 >> 1)];
      const float4 sv = *(const float4*)&sinc[pos * 32 + (dh0 >> 1)];
      const float cc[4] = {cv.x, cv.y, cv.z, cv.w};
      const float ss[4] = {sv.x, sv.y, sv.z, sv.w};
      u16x8 o;
#pragma unroll
      for (int p = 0; p < 4; ++p) {
        const float x1 = bf2f(v[2 * p]), x2 = bf2f(v[2 * p + 1]);
        o[2 * p]     = f2bf((x1 * cc[p] - x2 * ss[p]) * sc);
        o[2 * p + 1] = f2bf((x1 * ss[p] + x2 * cc[p]) * sc);
      }
      *(u16x8*)(dst + ((size_t)(b * Hn + h) * Tn + t) * DHn + dh0) = o;
    }
  } else {
    // ---- V: column read (conflict-free) -> V^T [b,h,dh,t] ----
    const int b  = (brow * 128) >> 11;     // block-uniform
    const int t0 = (brow * 128) & 2047;
#pragma unroll
    for (int ph = 0; ph < 8; ++ph) {
      const int task = ph * 256 + tid;
      const int col = task & 127;          // lane -> consecutive cols
      const int tg  = task >> 7;           // 0..15
      const int h  = 2 * (bcol - 16) + (col >> 6);
      const int dh = col & 63;
      u16x8 v;
#pragma unroll
      for (int j = 0; j < 8; ++j) v[j] = smem[(tg * 8 + j) * 136 + col];
      *(u16x8*)(vtb + ((size_t)(b * Hn + h) * DHn + dh) * Tn + t0 + tg * 8) = v;
    }
  }
}

// ---------------------------------------------------------------------------
// Kernel 2: causal flash attention. 512 blocks x 512 threads (8 waves),
// QBLK=128, KVBLK=128. K double-buffered (gload_lds); V SINGLE-buffered,
// staged early in-visit (latency hides under S+softmax; FIFO vmcnt(2)
// drains V only, K(t+1) stays in flight across barriers). Ps double-buffered
// PER HALF (32KB) -> pack(half1) no longer WAR-blocked on PV(half0) reads.
// LDS 80KB -> 2 blocks/CU. Pairing (lin, lin+256) -> qblk {a,15-a}.
// ---------------------------------------------------------------------------
__global__ __launch_bounds__(512) void k_attn(
    const u16* __restrict__ qbuf, const u16* __restrict__ kbuf,
    const u16* __restrict__ vtb, u16* __restrict__ ob)
{
  __shared__ u16 Ks[2][128][64];     // [buf][kv][dh]  32KB (linear, gload_lds)
  __shared__ u16 Vs[64][128];        // [dh][kv]       16KB single, staged in-visit
  __shared__ u16 Ps[2][8][16][64];   // [half][wave][q][kv64], XOR-swizzled  32KB

  const int tid  = threadIdx.x;
  const int lane = tid & 63, w = tid >> 6;           // w = 0..7
  const int l15 = lane & 15, l4 = lane >> 4;
  const int rsw  = l15 & 7;
  const int kgsw = ((lane & 7) ^ (lane >> 3)) * 8;   // K stage source granule

  const int lin = blockIdx.x;          // 0..511
  const int bh  = lin & 31;            // same 4 heads per XCD slot
  const int a   = (lin >> 5) & 7, rb = lin >> 8;     // rb = 0..1
  const int qblk = rb ? (15 - a) : a;                // pairs sum to uniform work
  const int b = bh >> 4, h = bh & 15;

  const u16* Qh = qbuf + (size_t)bh * Tn * DHn;
  const u16* Kh = kbuf + (size_t)bh * Tn * DHn;
  const u16* Vh = vtb  + (size_t)bh * DHn * Tn;

  const int q0 = qblk * 128 + w * 16;                // this wave's 16 q-rows
  const int ntiles = qblk + 1;                       // 128-wide KV tiles

  const s16x8 qf0 = *(const s16x8*)(Qh + (size_t)(q0 + l15) * 64 + l4 * 8);
  const s16x8 qf1 = *(const s16x8*)(Qh + (size_t)(q0 + l15) * 64 + 32 + l4 * 8);

  const s16x8 onesv = {(short)0x3F80, (short)0x3F80, (short)0x3F80, (short)0x3F80,
                       (short)0x3F80, (short)0x3F80, (short)0x3F80, (short)0x3F80};

  f32x4 o[4] = {};
  f32x4 o5 = {};                  // running sum l per q (ones-MFMA)
  float m = -3.0e38f;

  const int vl4 = lane >> 4;           // sub-row within a 4-row lds16 chunk

  // prologue: stage K tile 0 into buf0 (2 lds16 per wave); V staged in-visit
#pragma unroll
  for (int i = 0; i < 2; ++i) {
    const int kr = w * 16 + i * 8;
    lds16(&Ks[0][kr][0], Kh + (size_t)(kr + (lane >> 3)) * 64 + kgsw);
  }

  for (int it = 0; it < ntiles; ++it) {
    const int buf = it & 1;
    const int kv0 = it * 128;
    asm volatile("s_waitcnt vmcnt(0)" ::: "memory");   // K(t) landed
    __builtin_amdgcn_s_barrier();                      // K(t) visible; Vs free
    __builtin_amdgcn_sched_barrier(0);

    // issue V(t) FIRST (drained by vmcnt(2) before PV), then K(t+1)
#pragma unroll
    for (int i = 0; i < 2; ++i) {
      const int vr = w * 8 + i * 4;
      const int vrow = vr + vl4;
      lds16(&Vs[vr][0], Vh + (size_t)vrow * Tn + kv0 + ((lane & 15) ^ (vrow & 15)) * 8);
    }
    const bool havek1 = (it + 1 < ntiles);
    if (havek1) {
      const int nb = buf ^ 1;
      const int kv1 = kv0 + 128;
#pragma unroll
      for (int i = 0; i < 2; ++i) {
        const int kr = w * 16 + i * 8;
        lds16(&Ks[nb][kr][0], Kh + (size_t)(kv1 + kr + (lane >> 3)) * 64 + kgsw);
      }
    }

    // S^T = K Q^T over 8 quads: lane holds q=l15; kv = qd*16 + l4*4 + rr
    f32x4 s[8] = {};
    __builtin_amdgcn_s_setprio(1);
#pragma unroll
    for (int ks = 0; ks < 2; ++ks) {
      const s16x8 qf = ks ? qf1 : qf0;
      const int gr = ((ks * 4 + l4) ^ rsw) * 8;
#pragma unroll
      for (int qd = 0; qd < 8; ++qd) {
        const s16x8 kf = *(const s16x8*)&Ks[buf][qd * 16 + l15][gr];
        s[qd] = MFMA(kf, qf, s[qd]);
      }
    }
    __builtin_amdgcn_s_setprio(0);

    if (it == ntiles - 1) {          // diagonal region: causal mask
      const int kvb = kv0 + l4 * 4;
      const int qg  = q0 + l15;
#pragma unroll
      for (int qd = 0; qd < 8; ++qd)
#pragma unroll
        for (int rr = 0; rr < 4; ++rr)
          if (kvb + qd * 16 + rr > qg) s[qd][rr] = -3.0e38f;
    }

    // row max: per-quad max then tree of 8, + 2 shfl
    float qm[8];
#pragma unroll
    for (int qd = 0; qd < 8; ++qd)
      qm[qd] = fmaxf(fmaxf(s[qd][0], s[qd][1]), fmaxf(s[qd][2], s[qd][3]));
    float tmax = fmaxf(fmaxf(fmaxf(qm[0], qm[1]), fmaxf(qm[2], qm[3])),
                       fmaxf(fmaxf(qm[4], qm[5]), fmaxf(qm[6], qm[7])));
    tmax = fmaxf(tmax, __shfl_xor(tmax, 16));
    tmax = fmaxf(tmax, __shfl_xor(tmax, 32));

    if (__any(tmax > m + 8.0f)) {    // defer-max (exp2 domain)
      const float mn    = fmaxf(m, tmax);
      const float alpha = __builtin_amdgcn_exp2f(m - mn);
      m = mn;
#pragma unroll
      for (int n = 0; n < 4; ++n)
#pragma unroll
        for (int rr = 0; rr < 4; ++rr) o[n][rr] *= alpha;
#pragma unroll
      for (int rr = 0; rr < 4; ++rr) o5[rr] *= alpha;
    }

    // pack BOTH halves up-front (independent Ps buffers -> no WAR stall)
#pragma unroll
    for (int ph = 0; ph < 2; ++ph)
#pragma unroll
      for (int hl = 0; hl < 4; ++hl) {
        const int qd = ph * 4 + hl;
        u16x4 pk;
#pragma unroll
        for (int rr = 0; rr < 4; ++rr)
          pk[rr] = f2bf(__builtin_amdgcn_exp2f(s[qd][rr] - m));
        const int pg = ((hl << 1) + (l4 >> 1)) ^ rsw;
        *(u16x4*)&Ps[ph][w][l15][pg * 8 + (l4 & 1) * 4] = pk;
      }

    // drain V(t) (oldest 2 of {V,V,K1,K1}); K(t+1) stays in flight
    if (havek1) asm volatile("s_waitcnt vmcnt(2)" ::: "memory");
    else        asm volatile("s_waitcnt vmcnt(0)" ::: "memory");

    // PV halves: reads of Ps[0] / Ps[1] and the two MFMA chains overlap
    __builtin_amdgcn_s_setprio(1);
#pragma unroll
    for (int ph = 0; ph < 2; ++ph) {
      const s16x8 pf0 = *(const s16x8*)&Ps[ph][w][l15][(l4 ^ rsw) * 8];
      const s16x8 pf1 = *(const s16x8*)&Ps[ph][w][l15][((4 + l4) ^ rsw) * 8];
#pragma unroll
      for (int n = 0; n < 4; ++n) {
        const s16x8 vf0 =
            *(const s16x8*)&Vs[n * 16 + l15][((ph * 8 + l4) ^ l15) * 8];
        const s16x8 vf1 =
            *(const s16x8*)&Vs[n * 16 + l15][((ph * 8 + 4 + l4) ^ l15) * 8];
        o[n] = MFMA(vf0, pf0, o[n]);
        o[n] = MFMA(vf1, pf1, o[n]);
      }
      o5 = MFMA(onesv, pf0, o5);
      o5 = MFMA(onesv, pf1, o5);
    }
    __builtin_amdgcn_s_setprio(0);
    __builtin_amdgcn_sched_barrier(0);
    __builtin_amdgcn_s_barrier();    // PV reads of Vs/Ks[buf] done before overwrite
  }

  // normalize and store O bf16 [b,t,h*64+dh]
  const float inv = 1.0f / o5[0];
  const int t = q0 + l15;
#pragma unroll
  for (int n = 0; n < 4; ++n) {
    u16x4 ov;
#pragma unroll
    for (int rr = 0; rr < 4; ++rr) ov[rr] = f2bf(o[n][rr] * inv);
    *(u16x4*)(ob + (size_t)(b * Tn + t) * Dn + h * 64 + n * 16 + l4 * 4) = ov;
  }
}

// ---------------------------------------------------------------------------
// Kernel 3: out = O @ W_o^T (M=4096, N=1024, K=1024), fp32 out.
// 128x64 tile (grid 512), depth-2 counted-vmcnt pipeline + swizzle.
// ---------------------------------------------------------------------------
__global__ __launch_bounds__(256) void k_out(
    const u16* __restrict__ ob, const u16* __restrict__ wob,
    float* __restrict__ out)
{
  __shared__ u16 smem[24576];           // 48KB: As0|As1 (16KB ea) Bs0|Bs1 (8KB ea)
  const int tid  = threadIdx.x;
  const int bcol = blockIdx.x;          // 16 tiles of N=1024 (64 each)
  const int brow = blockIdx.y;          // 32 tiles of M=4096
  const int lane = tid & 63, w = tid >> 6;
  const int wr = w >> 1, wc = w & 1;    // wave quadrant: 64 rows x 32 cols
  const int l15 = lane & 15, l4 = lane >> 4;
  const int lrow = lane >> 3;
  const int gsw  = ((lane & 7) ^ (lane >> 3)) * 8;
  const int rsw  = l15 & 7;

  f32x4 acc[4][2] = {};

  // prologue: stage K-tile 0
#pragma unroll
  for (int c = 0; c < 4; ++c) {
    const int r0 = w * 32 + c * 8;
    lds16(&smem[r0 * 64], ob + (size_t)(brow * 128 + r0 + lrow) * 1024 + gsw);
  }
#pragma unroll
  for (int c = 0; c < 2; ++c) {
    const int r0 = w * 16 + c * 8;
    lds16(&smem[16384 + r0 * 64], wob + (size_t)(bcol * 64 + r0 + lrow) * 1024 + gsw);
  }

  for (int kt = 0; kt < 16; ++kt) {
    const int cur = kt & 1;
    const u16* Asb = smem + cur * 8192;
    const u16* Bsb = smem + 16384 + cur * 4096;
    if (kt < 15) {
      u16* Asn = smem + (cur ^ 1) * 8192;
      u16* Bsn = smem + 16384 + (cur ^ 1) * 4096;
      const int k1 = (kt + 1) * 64;
#pragma unroll
      for (int c = 0; c < 4; ++c) {
        const int r0 = w * 32 + c * 8;
        lds16(&Asn[r0 * 64], ob + (size_t)(brow * 128 + r0 + lrow) * 1024 + k1 + gsw);
      }
#pragma unroll
      for (int c = 0; c < 2; ++c) {
        const int r0 = w * 16 + c * 8;
        lds16(&Bsn[r0 * 64], wob + (size_t)(bcol * 64 + r0 + lrow) * 1024 + k1 + gsw);
      }
      asm volatile("s_waitcnt vmcnt(6)" ::: "memory");
    } else {
      asm volatile("s_waitcnt vmcnt(0)" ::: "memory");
    }
    __builtin_amdgcn_s_barrier();
    __builtin_amdgcn_sched_barrier(0);
    __builtin_amdgcn_s_setprio(1);
#pragma unroll
    for (int kk = 0; kk < 64; kk += 32) {
      const int gc = (kk >> 3) + l4;
      s16x8 af[4], bf[2];
#pragma unroll
      for (int m = 0; m < 4; ++m)
        af[m] = *(const s16x8*)&Asb[(wr * 64 + m * 16 + l15) * 64 + ((gc ^ rsw) * 8)];
#pragma unroll
      for (int n = 0; n < 2; ++n)
        bf[n] = *(const s16x8*)&Bsb[(wc * 32 + n * 16 + l15) * 64 + ((gc ^ rsw) * 8)];
#pragma unroll
      for (int m = 0; m < 4; ++m)
#pragma unroll
        for (int n = 0; n < 2; ++n)
          acc[m][n] = MFMA(af[m], bf[n], acc[m][n]);
    }
    __builtin_amdgcn_s_setprio(0);
    __builtin_amdgcn_sched_barrier(0);
    __builtin_amdgcn_s_barrier();
  }

#pragma unroll
  for (int m = 0; m < 4; ++m) {
    const int rowb = brow * 128 + wr * 64 + m * 16 + l4 * 4;
#pragma unroll
    for (int n = 0; n < 2; ++n) {
      const int colg = bcol * 64 + wc * 32 + n * 16 + l15;
#pragma unroll
      for (int r = 0; r < 4; ++r)
        out[(size_t)(rowb + r) * 1024 + colg] = acc[m][n][r];
    }
  }
}

// ---------------------------------------------------------------------------
extern "C" void kernel_launch(void* const* d_in, const int* in_sizes, int n_in,
                              void* d_out, int out_size, void* d_ws, size_t ws_size,
                              hipStream_t stream) {
  const float* x      = (const float*)d_in[0];
  const int*   tokpos = (const int*)d_in[1];
  const float* wqkv   = (const float*)d_in[2];
  const float* wo     = (const float*)d_in[3];
  const float* cosc   = (const float*)d_in[4];
  const float* sinc   = (const float*)d_in[5];
  float* out = (float*)d_out;

  // workspace (u16 units): xb 4M (reused as ob), wqkvb 3M, qb/kb/vtb 4M each,
  // wob 1M (own region -> wo convert can run in the single up-front cvt)
  u16* xb    = (u16*)d_ws;
  u16* wqkvb = xb + (size_t)Bn * Tn * Dn;
  u16* qb    = wqkvb + (size_t)3 * Dn * Dn;
  u16* kb    = qb + (size_t)Bn * Tn * Dn;
  u16* vtb   = kb + (size_t)Bn * Tn * Dn;
  u16* wob   = vtb + (size_t)Bn * Tn * Dn;
  u16* ob    = xb;      // xb dead after k_qkv

  dim3 blk(256);
  k_cvt3<<<dim3(2048), blk, 0, stream>>>(x, (Bn * Tn * Dn) / 4,
                                         wqkv, (3 * Dn * Dn) / 4,
                                         wo, (Dn * Dn) / 4, xb, wob);

  k_qkv<<<dim3(24, 32), blk, 0, stream>>>(xb, wqkvb, tokpos, cosc, sinc, qb, kb, vtb);

  k_attn<<<dim3(512), dim3(512), 0, stream>>>(qb, kb, vtb, ob);

  k_out<<<dim3(16, 32), blk, 0, stream>>>(ob, wob, out);
}

// Round 13
// 97.531 us; speedup vs baseline: 1.0242x; 1.0242x over previous
//
#include <hip/hip_runtime.h>
#include <hip/hip_bf16.h>
#include <stdint.h>

// Problem constants (B=2, T=2048, D=1024, H=16, DH=64)
#define Bn  2
#define Tn  2048
#define Dn  1024
#define Hn  16
#define DHn 64
#define QSCALE 0.1803368801111204f   // 0.125 * log2(e): fold softmax scale + exp2 into Q

typedef unsigned short u16;
typedef __attribute__((ext_vector_type(8))) short s16x8;            // 8 bf16 MFMA frag
typedef __attribute__((ext_vector_type(8))) unsigned short u16x8;
typedef __attribute__((ext_vector_type(4))) unsigned short u16x4;
typedef __attribute__((ext_vector_type(4))) float f32x4;

#define MFMA(a, b, c) __builtin_amdgcn_mfma_f32_16x16x32_bf16((a), (b), (c), 0, 0, 0)

__device__ __forceinline__ u16 f2bf(float f) {
  union { __hip_bfloat16 b; u16 u; } c;
  c.b = __float2bfloat16(f);
  return c.u;
}
__device__ __forceinline__ float bf2f(u16 u) {
  union { u16 u; __hip_bfloat16 b; } c;
  c.u = u;
  return __bfloat162float(c.b);
}

// async global->LDS, 16B per lane; LDS dest is wave-uniform base (+lane*16)
__device__ __forceinline__ void lds16(void* lds, const void* g) {
  __builtin_amdgcn_global_load_lds((__attribute__((address_space(1))) void*)(g),
                                   (__attribute__((address_space(3))) void*)(lds), 16, 0, 0);
}

// ---------------------------------------------------------------------------
// fp32 -> bf16 bulk convert: x, W_qkv, W_o in ONE launch.
// ---------------------------------------------------------------------------
__global__ __launch_bounds__(256) void k_cvt3(
    const float* __restrict__ s0, int n0,
    const float* __restrict__ s1, int n1,
    const float* __restrict__ s2, int n2,
    u16* __restrict__ d01, u16* __restrict__ d2) {
  int i = blockIdx.x * blockDim.x + threadIdx.x;
  const int stride = gridDim.x * blockDim.x;
  const int nt = n0 + n1 + n2;
  for (; i < nt; i += stride) {
    float4 v;
    u16x4 o;
    if (i < n0 + n1) {
      v = (i < n0) ? ((const float4*)s0)[i] : ((const float4*)s1)[i - n0];
      o[0] = f2bf(v.x); o[1] = f2bf(v.y); o[2] = f2bf(v.z); o[3] = f2bf(v.w);
      ((u16x4*)d01)[i] = o;
    } else {
      v = ((const float4*)s2)[i - n0 - n1];
      o[0] = f2bf(v.x); o[1] = f2bf(v.y); o[2] = f2bf(v.z); o[3] = f2bf(v.w);
      ((u16x4*)d2)[i - n0 - n1] = o;
    }
  }
}

// ---------------------------------------------------------------------------
// Kernel 1: qkv = x @ W_qkv^T (M=4096, N=3072, K=1024).
// BK=32, depth-2 counted-vmcnt pipeline, 34.8KB LDS -> 4 blocks/CU.
// XOR-granule swizzle. Blocks pure Q(0-7)/K(8-15)/V(16-23).
// Epilogue: acc -> LDS (stride 136); Q/K RoPE + coalesced stores; V
// column-transpose -> V^T [b,h,dh,t].
// ---------------------------------------------------------------------------
__global__ __launch_bounds__(256) void k_qkv(
    const u16* __restrict__ xb, const u16* __restrict__ wb,
    const int* __restrict__ tokpos,
    const float* __restrict__ cosc, const float* __restrict__ sinc,
    u16* __restrict__ qb, u16* __restrict__ kb, u16* __restrict__ vtb)
{
  __shared__ u16 smem[17408];           // loop: As0|As1|Bs0|Bs1 (8KB each); epi 34.8KB
  const int tid  = threadIdx.x;
  const int bcol = blockIdx.x;          // 24 tiles of N=3072
  const int brow = blockIdx.y;          // 32 tiles of M=4096
  const int lane = tid & 63, w = tid >> 6;
  const int wr = w >> 1, wc = w & 1;
  const int l15 = lane & 15, l4 = lane >> 4;
  const int lrow = lane >> 2;                        // 0..15 (4 lanes/32-elem row)
  const int gsw  = (((lane & 3) ^ ((lrow >> 1) & 3)) * 8);  // src granule (u16 units)
  const int rsw  = (l15 >> 1) & 3;                   // frag-read granule XOR

  const u16* xrow = xb + (size_t)(brow * 128) * 1024;
  const u16* wrow = wb + (size_t)(bcol * 128) * 1024;

  f32x4 acc[4][4] = {};

  // prologue: stage k-step 0 into buf0 (4 lds16 per wave)
  {
    const int r0 = w * 32;
    lds16(&smem[r0 * 32],              xrow + (size_t)(r0 + lrow) * 1024 + gsw);
    lds16(&smem[(r0 + 16) * 32],       xrow + (size_t)(r0 + 16 + lrow) * 1024 + gsw);
    lds16(&smem[8192 + r0 * 32],       wrow + (size_t)(r0 + lrow) * 1024 + gsw);
    lds16(&smem[8192 + (r0 + 16) * 32],wrow + (size_t)(r0 + 16 + lrow) * 1024 + gsw);
  }

  for (int kt = 0; kt < 32; ++kt) {
    const int cur = kt & 1;
    const u16* Asb = smem + cur * 4096;
    const u16* Bsb = smem + 8192 + cur * 4096;
    if (kt < 31) {                       // stage(t+1): stays in flight through compute
      u16* Asn = smem + (cur ^ 1) * 4096;
      u16* Bsn = smem + 8192 + (cur ^ 1) * 4096;
      const int k1 = (kt + 1) * 32;
      const int r0 = w * 32;
      lds16(&Asn[r0 * 32],        xrow + (size_t)(r0 + lrow) * 1024 + k1 + gsw);
      lds16(&Asn[(r0 + 16) * 32], xrow + (size_t)(r0 + 16 + lrow) * 1024 + k1 + gsw);
      lds16(&Bsn[r0 * 32],        wrow + (size_t)(r0 + lrow) * 1024 + k1 + gsw);
      lds16(&Bsn[(r0 + 16) * 32], wrow + (size_t)(r0 + 16 + lrow) * 1024 + k1 + gsw);
      asm volatile("s_waitcnt vmcnt(4)" ::: "memory");   // stage(t) complete
    } else {
      asm volatile("s_waitcnt vmcnt(0)" ::: "memory");
    }
    __builtin_amdgcn_s_barrier();        // buf(t) visible to all waves
    __builtin_amdgcn_sched_barrier(0);
    __builtin_amdgcn_s_setprio(1);
    {
      const int gr = (l4 ^ rsw) * 8;
      s16x8 af[4], bf[4];
#pragma unroll
      for (int m = 0; m < 4; ++m)
        af[m] = *(const s16x8*)&Asb[(wr * 64 + m * 16 + l15) * 32 + gr];
#pragma unroll
      for (int n = 0; n < 4; ++n)
        bf[n] = *(const s16x8*)&Bsb[(wc * 64 + n * 16 + l15) * 32 + gr];
#pragma unroll
      for (int m = 0; m < 4; ++m)
#pragma unroll
        for (int n = 0; n < 4; ++n)
          acc[m][n] = MFMA(af[m], bf[n], acc[m][n]);
    }
    __builtin_amdgcn_s_setprio(0);
    __builtin_amdgcn_sched_barrier(0);
    __builtin_amdgcn_s_barrier();        // all reads of buf(t) done before overwrite
  }

  // ---- epilogue phase 1: raw acc -> Ct (bf16, stride 136) ----
#pragma unroll
  for (int m = 0; m < 4; ++m)
#pragma unroll
    for (int n = 0; n < 4; ++n)
#pragma unroll
      for (int r = 0; r < 4; ++r)
        smem[(wr * 64 + m * 16 + l4 * 4 + r) * 136 + wc * 64 + n * 16 + l15] =
            f2bf(acc[m][n][r]);
  __syncthreads();

  if (bcol < 16) {
    // ---- Q/K: re-read rows, RoPE in-register, coalesced 16B stores ----
    u16* dst; float sc;
    if (bcol < 8) { dst = qb; sc = QSCALE; } else { dst = kb; sc = 1.0f; }
#pragma unroll
    for (int ph = 0; ph < 8; ++ph) {
      const int task = ph * 256 + tid;
      const int lr   = task >> 4;          // 0..127
      const int cg   = task & 15;          // col group (8 elems)
      const int rowg = brow * 128 + lr;
      const int b = rowg >> 11, t = rowg & 2047;
      const int rem = (bcol * 128 + cg * 8) & 1023;
      const int h = rem >> 6, dh0 = rem & 63;
      u16x8 v = *(const u16x8*)&smem[lr * 136 + cg * 8];
      const int pos = tokpos[t];
      const float4 cv = *(const float4*)&cosc[pos * 32 + (dh0 >> 1)];
      const float4 sv = *(const float4*)&sinc[pos * 32 + (dh0 >> 1)];
      const float cc[4] = {cv.x, cv.y, cv.z, cv.w};
      const float ss[4] = {sv.x, sv.y, sv.z, sv.w};
      u16x8 o;
#pragma unroll
      for (int p = 0; p < 4; ++p) {
        const float x1 = bf2f(v[2 * p]), x2 = bf2f(v[2 * p + 1]);
        o[2 * p]     = f2bf((x1 * cc[p] - x2 * ss[p]) * sc);
        o[2 * p + 1] = f2bf((x1 * ss[p] + x2 * cc[p]) * sc);
      }
      *(u16x8*)(dst + ((size_t)(b * Hn + h) * Tn + t) * DHn + dh0) = o;
    }
  } else {
    // ---- V: column read (conflict-free) -> V^T [b,h,dh,t] ----
    const int b  = (brow * 128) >> 11;     // block-uniform
    const int t0 = (brow * 128) & 2047;
#pragma unroll
    for (int ph = 0; ph < 8; ++ph) {
      const int task = ph * 256 + tid;
      const int col = task & 127;          // lane -> consecutive cols
      const int tg  = task >> 7;           // 0..15
      const int h  = 2 * (bcol - 16) + (col >> 6);
      const int dh = col & 63;
      u16x8 v;
#pragma unroll
      for (int j = 0; j < 8; ++j) v[j] = smem[(tg * 8 + j) * 136 + col];
      *(u16x8*)(vtb + ((size_t)(b * Hn + h) * DHn + dh) * Tn + t0 + tg * 8) = v;
    }
  }
}

// ---------------------------------------------------------------------------
// Kernel 2: causal flash attention. 512 blocks x 512 threads (8 waves),
// QBLK=128, KVBLK=128. K and V SINGLE-buffered, staged in-visit with
// airtight sync (every cross-wave consume is producer-vmcnt -> barrier
// protected): barrier(A) -> issue K,V -> vmcnt(2)[K] -> barrier(B) ->
// S+softmax+pack0 (V in flight) -> vmcnt(0)[V] -> barrier(C) -> PV.
// LDS 48KB -> 3 blocks/CU: cross-block overlap hides the in-visit load
// latency (m114 mechanism). Pairing (lin, lin+256) -> qblk {a,15-a}.
// ---------------------------------------------------------------------------
__global__ __launch_bounds__(512) void k_attn(
    const u16* __restrict__ qbuf, const u16* __restrict__ kbuf,
    const u16* __restrict__ vtb, u16* __restrict__ ob)
{
  __shared__ u16 Ks[128][64];     // [kv][dh]  16KB single (linear, gload_lds)
  __shared__ u16 Vs[64][128];     // [dh][kv]  16KB single (row-swizzled granules)
  __shared__ u16 Ps[8][16][64];   // per-wave P^T [q][kv64], XOR-swizzled  16KB

  const int tid  = threadIdx.x;
  const int lane = tid & 63, w = tid >> 6;           // w = 0..7
  const int l15 = lane & 15, l4 = lane >> 4;
  const int rsw  = l15 & 7;
  const int kgsw = ((lane & 7) ^ (lane >> 3)) * 8;   // K stage source granule

  const int lin = blockIdx.x;          // 0..511
  const int bh  = lin & 31;            // same 4 heads per XCD slot
  const int a   = (lin >> 5) & 7, rb = lin >> 8;     // rb = 0..1
  const int qblk = rb ? (15 - a) : a;                // pairs sum to uniform work
  const int b = bh >> 4, h = bh & 15;

  const u16* Qh = qbuf + (size_t)bh * Tn * DHn;
  const u16* Kh = kbuf + (size_t)bh * Tn * DHn;
  const u16* Vh = vtb  + (size_t)bh * DHn * Tn;

  const int q0 = qblk * 128 + w * 16;                // this wave's 16 q-rows
  const int ntiles = qblk + 1;                       // 128-wide KV tiles

  const s16x8 qf0 = *(const s16x8*)(Qh + (size_t)(q0 + l15) * 64 + l4 * 8);
  const s16x8 qf1 = *(const s16x8*)(Qh + (size_t)(q0 + l15) * 64 + 32 + l4 * 8);

  const s16x8 onesv = {(short)0x3F80, (short)0x3F80, (short)0x3F80, (short)0x3F80,
                       (short)0x3F80, (short)0x3F80, (short)0x3F80, (short)0x3F80};

  f32x4 o[4] = {};
  f32x4 o5 = {};                  // running sum l per q (ones-MFMA)
  float m = -3.0e38f;

  const int vl4 = lane >> 4;           // sub-row within a 4-row lds16 chunk

  for (int it = 0; it < ntiles; ++it) {
    const int kv0 = it * 128;

    __builtin_amdgcn_s_barrier();        // A: prev visit's LDS reads complete
    __builtin_amdgcn_sched_barrier(0);

    // issue K(t) FIRST (drained by vmcnt(2)), then V(t)
#pragma unroll
    for (int i = 0; i < 2; ++i) {
      const int kr = w * 16 + i * 8;
      lds16(&Ks[kr][0], Kh + (size_t)(kv0 + kr + (lane >> 3)) * 64 + kgsw);
    }
#pragma unroll
    for (int i = 0; i < 2; ++i) {
      const int vr = w * 8 + i * 4;
      const int vrow = vr + vl4;
      lds16(&Vs[vr][0], Vh + (size_t)vrow * Tn + kv0 + ((lane & 15) ^ (vrow & 15)) * 8);
    }
    asm volatile("s_waitcnt vmcnt(2)" ::: "memory");   // own K landed
    __builtin_amdgcn_s_barrier();        // B: ALL waves' K landed (cross-wave safe)
    __builtin_amdgcn_sched_barrier(0);

    // S^T = K Q^T over 8 quads: lane holds q=l15; kv = qd*16 + l4*4 + rr
    f32x4 s[8] = {};
    __builtin_amdgcn_s_setprio(1);
#pragma unroll
    for (int ks = 0; ks < 2; ++ks) {
      const s16x8 qf = ks ? qf1 : qf0;
      const int gr = ((ks * 4 + l4) ^ rsw) * 8;
#pragma unroll
      for (int qd = 0; qd < 8; ++qd) {
        const s16x8 kf = *(const s16x8*)&Ks[qd * 16 + l15][gr];
        s[qd] = MFMA(kf, qf, s[qd]);
      }
    }
    __builtin_amdgcn_s_setprio(0);

    if (it == ntiles - 1) {          // diagonal region: causal mask
      const int kvb = kv0 + l4 * 4;
      const int qg  = q0 + l15;
#pragma unroll
      for (int qd = 0; qd < 8; ++qd)
#pragma unroll
        for (int rr = 0; rr < 4; ++rr)
          if (kvb + qd * 16 + rr > qg) s[qd][rr] = -3.0e38f;
    }

    // row max: per-quad max then tree of 8, + 2 shfl
    float qm[8];
#pragma unroll
    for (int qd = 0; qd < 8; ++qd)
      qm[qd] = fmaxf(fmaxf(s[qd][0], s[qd][1]), fmaxf(s[qd][2], s[qd][3]));
    float tmax = fmaxf(fmaxf(fmaxf(qm[0], qm[1]), fmaxf(qm[2], qm[3])),
                       fmaxf(fmaxf(qm[4], qm[5]), fmaxf(qm[6], qm[7])));
    tmax = fmaxf(tmax, __shfl_xor(tmax, 16));
    tmax = fmaxf(tmax, __shfl_xor(tmax, 32));

    if (__any(tmax > m + 8.0f)) {    // defer-max (exp2 domain)
      const float mn    = fmaxf(m, tmax);
      const float alpha = __builtin_amdgcn_exp2f(m - mn);
      m = mn;
#pragma unroll
      for (int n = 0; n < 4; ++n)
#pragma unroll
        for (int rr = 0; rr < 4; ++rr) o[n][rr] *= alpha;
#pragma unroll
      for (int rr = 0; rr < 4; ++rr) o5[rr] *= alpha;
    }

    // pack half 0 into Ps while V is still in flight
#pragma unroll
    for (int hl = 0; hl < 4; ++hl) {
      u16x4 pk;
#pragma unroll
      for (int rr = 0; rr < 4; ++rr)
        pk[rr] = f2bf(__builtin_amdgcn_exp2f(s[hl][rr] - m));
      const int pg = ((hl << 1) + (l4 >> 1)) ^ rsw;
      *(u16x4*)&Ps[w][l15][pg * 8 + (l4 & 1) * 4] = pk;
    }

    asm volatile("s_waitcnt vmcnt(0)" ::: "memory");   // own V landed
    __builtin_amdgcn_s_barrier();        // C: ALL waves' V landed (cross-wave safe)
    __builtin_amdgcn_sched_barrier(0);

    // PV halves (Ps per-wave: pack(half1) WAR on PV(half0) handled by lgkmcnt)
    __builtin_amdgcn_s_setprio(1);
#pragma unroll
    for (int ph = 0; ph < 2; ++ph) {
      if (ph == 1) {                    // pack half 1
#pragma unroll
        for (int hl = 0; hl < 4; ++hl) {
          const int qd = 4 + hl;
          u16x4 pk;
#pragma unroll
          for (int rr = 0; rr < 4; ++rr)
            pk[rr] = f2bf(__builtin_amdgcn_exp2f(s[qd][rr] - m));
          const int pg = ((hl << 1) + (l4 >> 1)) ^ rsw;
          *(u16x4*)&Ps[w][l15][pg * 8 + (l4 & 1) * 4] = pk;
        }
      }
      const s16x8 pf0 = *(const s16x8*)&Ps[w][l15][(l4 ^ rsw) * 8];
      const s16x8 pf1 = *(const s16x8*)&Ps[w][l15][((4 + l4) ^ rsw) * 8];
#pragma unroll
      for (int n = 0; n < 4; ++n) {
        const s16x8 vf0 =
            *(const s16x8*)&Vs[n * 16 + l15][((ph * 8 + l4) ^ l15) * 8];
        const s16x8 vf1 =
            *(const s16x8*)&Vs[n * 16 + l15][((ph * 8 + 4 + l4) ^ l15) * 8];
        o[n] = MFMA(vf0, pf0, o[n]);
        o[n] = MFMA(vf1, pf1, o[n]);
      }
      o5 = MFMA(onesv, pf0, o5);
      o5 = MFMA(onesv, pf1, o5);
    }
    __builtin_amdgcn_s_setprio(0);
    __builtin_amdgcn_sched_barrier(0);
  }

  // normalize and store O bf16 [b,t,h*64+dh]
  const float inv = 1.0f / o5[0];
  const int t = q0 + l15;
#pragma unroll
  for (int n = 0; n < 4; ++n) {
    u16x4 ov;
#pragma unroll
    for (int rr = 0; rr < 4; ++rr) ov[rr] = f2bf(o[n][rr] * inv);
    *(u16x4*)(ob + (size_t)(b * Tn + t) * Dn + h * 64 + n * 16 + l4 * 4) = ov;
  }
}

// ---------------------------------------------------------------------------
// Kernel 3: out = O @ W_o^T (M=4096, N=1024, K=1024), fp32 out.
// 128x64 tile (grid 512), depth-2 counted-vmcnt pipeline + swizzle.
// ---------------------------------------------------------------------------
__global__ __launch_bounds__(256) void k_out(
    const u16* __restrict__ ob, const u16* __restrict__ wob,
    float* __restrict__ out)
{
  __shared__ u16 smem[24576];           // 48KB: As0|As1 (16KB ea) Bs0|Bs1 (8KB ea)
  const int tid  = threadIdx.x;
  const int bcol = blockIdx.x;          // 16 tiles of N=1024 (64 each)
  const int brow = blockIdx.y;          // 32 tiles of M=4096
  const int lane = tid & 63, w = tid >> 6;
  const int wr = w >> 1, wc = w & 1;    // wave quadrant: 64 rows x 32 cols
  const int l15 = lane & 15, l4 = lane >> 4;
  const int lrow = lane >> 3;
  const int gsw  = ((lane & 7) ^ (lane >> 3)) * 8;
  const int rsw  = l15 & 7;

  f32x4 acc[4][2] = {};

  // prologue: stage K-tile 0
#pragma unroll
  for (int c = 0; c < 4; ++c) {
    const int r0 = w * 32 + c * 8;
    lds16(&smem[r0 * 64], ob + (size_t)(brow * 128 + r0 + lrow) * 1024 + gsw);
  }
#pragma unroll
  for (int c = 0; c < 2; ++c) {
    const int r0 = w * 16 + c * 8;
    lds16(&smem[16384 + r0 * 64], wob + (size_t)(bcol * 64 + r0 + lrow) * 1024 + gsw);
  }

  for (int kt = 0; kt < 16; ++kt) {
    const int cur = kt & 1;
    const u16* Asb = smem + cur * 8192;
    const u16* Bsb = smem + 16384 + cur * 4096;
    if (kt < 15) {
      u16* Asn = smem + (cur ^ 1) * 8192;
      u16* Bsn = smem + 16384 + (cur ^ 1) * 4096;
      const int k1 = (kt + 1) * 64;
#pragma unroll
      for (int c = 0; c < 4; ++c) {
        const int r0 = w * 32 + c * 8;
        lds16(&Asn[r0 * 64], ob + (size_t)(brow * 128 + r0 + lrow) * 1024 + k1 + gsw);
      }
#pragma unroll
      for (int c = 0; c < 2; ++c) {
        const int r0 = w * 16 + c * 8;
        lds16(&Bsn[r0 * 64], wob + (size_t)(bcol * 64 + r0 + lrow) * 1024 + k1 + gsw);
      }
      asm volatile("s_waitcnt vmcnt(6)" ::: "memory");
    } else {
      asm volatile("s_waitcnt vmcnt(0)" ::: "memory");
    }
    __builtin_amdgcn_s_barrier();
    __builtin_amdgcn_sched_barrier(0);
    __builtin_amdgcn_s_setprio(1);
#pragma unroll
    for (int kk = 0; kk < 64; kk += 32) {
      const int gc = (kk >> 3) + l4;
      s16x8 af[4], bf[2];
#pragma unroll
      for (int m = 0; m < 4; ++m)
        af[m] = *(const s16x8*)&Asb[(wr * 64 + m * 16 + l15) * 64 + ((gc ^ rsw) * 8)];
#pragma unroll
      for (int n = 0; n < 2; ++n)
        bf[n] = *(const s16x8*)&Bsb[(wc * 32 + n * 16 + l15) * 64 + ((gc ^ rsw) * 8)];
#pragma unroll
      for (int m = 0; m < 4; ++m)
#pragma unroll
        for (int n = 0; n < 2; ++n)
          acc[m][n] = MFMA(af[m], bf[n], acc[m][n]);
    }
    __builtin_amdgcn_s_setprio(0);
    __builtin_amdgcn_sched_barrier(0);
    __builtin_amdgcn_s_barrier();
  }

#pragma unroll
  for (int m = 0; m < 4; ++m) {
    const int rowb = brow * 128 + wr * 64 + m * 16 + l4 * 4;
#pragma unroll
    for (int n = 0; n < 2; ++n) {
      const int colg = bcol * 64 + wc * 32 + n * 16 + l15;
#pragma unroll
      for (int r = 0; r < 4; ++r)
        out[(size_t)(rowb + r) * 1024 + colg] = acc[m][n][r];
    }
  }
}

// ---------------------------------------------------------------------------
extern "C" void kernel_launch(void* const* d_in, const int* in_sizes, int n_in,
                              void* d_out, int out_size, void* d_ws, size_t ws_size,
                              hipStream_t stream) {
  const float* x      = (const float*)d_in[0];
  const int*   tokpos = (const int*)d_in[1];
  const float* wqkv   = (const float*)d_in[2];
  const float* wo     = (const float*)d_in[3];
  const float* cosc   = (const float*)d_in[4];
  const float* sinc   = (const float*)d_in[5];
  float* out = (float*)d_out;

  // workspace (u16 units): xb 4M (reused as ob), wqkvb 3M, qb/kb/vtb 4M each,
  // wob 1M
  u16* xb    = (u16*)d_ws;
  u16* wqkvb = xb + (size_t)Bn * Tn * Dn;
  u16* qb    = wqkvb + (size_t)3 * Dn * Dn;
  u16* kb    = qb + (size_t)Bn * Tn * Dn;
  u16* vtb   = kb + (size_t)Bn * Tn * Dn;
  u16* wob   = vtb + (size_t)Bn * Tn * Dn;
  u16* ob    = xb;      // xb dead after k_qkv

  dim3 blk(256);
  k_cvt3<<<dim3(2048), blk, 0, stream>>>(x, (Bn * Tn * Dn) / 4,
                                         wqkv, (3 * Dn * Dn) / 4,
                                         wo, (Dn * Dn) / 4, xb, wob);

  k_qkv<<<dim3(24, 32), blk, 0, stream>>>(xb, wqkvb, tokpos, cosc, sinc, qb, kb, vtb);

  k_attn<<<dim3(512), dim3(512), 0, stream>>>(qb, kb, vtb, ob);

  k_out<<<dim3(16, 32), blk, 0, stream>>>(ob, wob, out);
}